// Round 7
// baseline (660.487 us; speedup 1.0000x reference)
//
#include <hip/hip_runtime.h>
#include <hip/hip_bf16.h>
#include <math.h>

#define S 1024
#define D 1024
#define P 2816
#define R 64
#define E 8
#define M 16
#define KSPLIT 4
#define KQ (P / KSPLIT)        // 704
#define NIT (KQ / 64)          // 11
#define ZT 4                   // P1 K-split (z) x 4 waves = 16 K-slices of 64
#define ACH ((E * P * R) / 8)  // 180224 adapter short8-chunks
#define NBLK 512

typedef __attribute__((ext_vector_type(8))) short short8;   // 8 bf16 (4 VGPRs)
typedef __attribute__((ext_vector_type(4))) float floatx4;  // MFMA acc

static __device__ inline unsigned short f2bf(float f) {
  __hip_bfloat16 h = __float2bfloat16(f);
  return *reinterpret_cast<unsigned short*>(&h);
}
static __device__ inline short8 pack8(float4 a, float4 b) {
  short8 v;
  v[0] = f2bf(a.x); v[1] = f2bf(a.y); v[2] = f2bf(a.z); v[3] = f2bf(a.w);
  v[4] = f2bf(b.x); v[5] = f2bf(b.y); v[6] = f2bf(b.z); v[7] = f2bf(b.w);
  return v;
}

// Hand-rolled grid barrier (G16 pattern): one FRESH counter per phase (no
// reset race), device-scope release add + acquire-load spin. Requires all
// NBLK blocks co-resident: 512 blocks @ 46080B LDS = 3/CU -> 768 capacity.
static __device__ __forceinline__ void gbar(unsigned* ctr) {
  __syncthreads();
  if (threadIdx.x == 0) {
    __threadfence();  // release this block's stores to device scope
    __hip_atomic_fetch_add(ctr, 1u, __ATOMIC_RELEASE, __HIP_MEMORY_SCOPE_AGENT);
    while (__hip_atomic_load(ctr, __ATOMIC_ACQUIRE, __HIP_MEMORY_SCOPE_AGENT) < NBLK)
      __builtin_amdgcn_s_sleep(4);
    __threadfence();  // acquire: invalidate stale L1/L2 before phase reads
  }
  __syncthreads();
}

// ---------------------------------------------------------------------------
// ONE kernel, 512 blocks x 256 threads, 5 phases split by gbar(). Phase
// bodies are the round-5 verified per-kernel loops, LDS union'd into 46080 B.
// Rationale unchanged from round 6: 7 serialized dispatches cost ~8-12 us
// each in launch/gap/tail while total in-kernel arithmetic is ~30 us.
// Round-6 failure was the LAUNCHER (cooperative launch no-ops under graph
// capture -> output stayed memset-zero; absmax 2^-7 == max|ref|), not the
// phase logic.
// ---------------------------------------------------------------------------
__global__ __launch_bounds__(256) void k_mega(
    const float* __restrict__ H, const int* __restrict__ idx,
    const float* __restrict__ wts, const float* __restrict__ Aup,
    const float* __restrict__ Agate, const float* __restrict__ upl,
    const float* __restrict__ gatel, const float* __restrict__ Wd,
    const float* __restrict__ upb, const float* __restrict__ gateb,
    unsigned short* __restrict__ Hbf, unsigned short* __restrict__ mxT,
    unsigned short* __restrict__ Aubf, unsigned short* __restrict__ Agbf,
    unsigned short* __restrict__ inter, float* __restrict__ tpart,
    float* __restrict__ dpart, int* __restrict__ perm,
    int* __restrict__ offs, float* __restrict__ out,
    unsigned* __restrict__ bars) {
  __shared__ __align__(16) unsigned char smem[46080];
  int b = blockIdx.x, t = threadIdx.x;
  int lane = t & 63, w = t >> 6, quad = lane >> 4, l15 = lane & 15;

  // ========== P0: sort (b==0) + H/adapter->bf16 (b<256) + mix (256<=b<384) ==
  if (b < 256) {
    int g = b * 256 + t;
    if (b == 0) {  // counting sort, 4 tokens/thread
      int* hist = (int*)smem;
      int* basearr = hist + E;
      if (t < E) hist[t] = 0;
      __syncthreads();
      int e4[4];
#pragma unroll
      for (int j = 0; j < 4; ++j) {
        e4[j] = idx[t + j * 256];
        atomicAdd(&hist[e4[j]], 1);
      }
      __syncthreads();
      if (t == 0) {
        int run = 0;
        for (int i = 0; i < E; ++i) { basearr[i] = run; offs[i] = run; run += hist[i]; }
        offs[E] = S;
      }
      __syncthreads();
#pragma unroll
      for (int j = 0; j < 4; ++j) {
        int pos = atomicAdd(&basearr[e4[j]], 1);
        perm[pos] = t + j * 256;
      }
    }
    // H -> bf16, 16 elems/thread (coalesced)
    {
      const float* hs = H + (size_t)g * 16;
      float4 h0 = *(const float4*)hs, h1 = *(const float4*)(hs + 4);
      float4 h2 = *(const float4*)(hs + 8), h3 = *(const float4*)(hs + 12);
      *(short8*)(Hbf + (size_t)g * 16) = pack8(h0, h1);
      *(short8*)(Hbf + (size_t)g * 16 + 8) = pack8(h2, h3);
    }
    // adapters -> bf16 (strided over short8 chunks)
#pragma unroll
    for (int j = 0; j < 3; ++j) {
      int c = g + j * 65536;
      if (c < ACH) {
        const float* su = Aup + (size_t)c * 8;
        const float* sg = Agate + (size_t)c * 8;
        float4 u0 = *(const float4*)su, u1 = *(const float4*)(su + 4);
        float4 g0 = *(const float4*)sg, g1 = *(const float4*)(sg + 4);
        *(short8*)(Aubf + (size_t)c * 8) = pack8(u0, u1);
        *(short8*)(Agbf + (size_t)c * 8) = pack8(g0, g1);
      }
    }
  } else if (b < 384) {
    // mix: block = (mat, d0 of 16). Bank read once, coalesced over r;
    // LDS-transposed; mxT written in contiguous 32B row-chunks.
    int mb = b - 256;
    int mat = mb >> 6, d0 = (mb & 63) * 16;
    const float* bank = mat ? gateb : upb;
    float* tile = (float*)smem;              // [E][64][17] f32 = 34816 B
    float* alpha = (float*)(smem + 34816);   // [E][M] = 512 B
    if (t < E) {
      const float* lg = (mat ? gatel : upl) + t * M;
      float v[M], mx = -1e30f, s = 0.f;
#pragma unroll
      for (int m = 0; m < M; ++m) { v[m] = lg[m]; mx = fmaxf(mx, v[m]); }
#pragma unroll
      for (int m = 0; m < M; ++m) { v[m] = expf(v[m] - mx); s += v[m]; }
#pragma unroll
      for (int m = 0; m < M; ++m) alpha[t * M + m] = v[m] / s;
    }
    __syncthreads();
    int r4 = (t & 15) * 4;  // r base: thread covers r4..r4+3
    int dg = t >> 4;        // d-local 0..15
    float val[E][4];
#pragma unroll
    for (int e = 0; e < E; ++e)
#pragma unroll
      for (int i = 0; i < 4; ++i) val[e][i] = 0.f;
    for (int m = 0; m < M; ++m) {
      float4 bv = *(const float4*)(bank + ((size_t)m * D + d0 + dg) * R + r4);
#pragma unroll
      for (int e = 0; e < E; ++e) {
        float a = alpha[e * M + m];
        val[e][0] += a * bv.x; val[e][1] += a * bv.y;
        val[e][2] += a * bv.z; val[e][3] += a * bv.w;
      }
    }
#pragma unroll
    for (int e = 0; e < E; ++e)
#pragma unroll
      for (int i = 0; i < 4; ++i) tile[((size_t)e * 64 + r4 + i) * 17 + dg] = val[e][i];
    __syncthreads();
    int e = t >> 5;
#pragma unroll
    for (int half = 0; half < 2; ++half) {
      int rr = (t & 31) + half * 32;
      short8 o0, o1;
#pragma unroll
      for (int j = 0; j < 8; ++j) {
        o0[j] = (short)f2bf(tile[((size_t)e * 64 + rr) * 17 + j]);
        o1[j] = (short)f2bf(tile[((size_t)e * 64 + rr) * 17 + 8 + j]);
      }
      unsigned short* dst = mxT + ((size_t)(e * 128 + mat * 64 + rr)) * D + d0;
      *(short8*)dst = o0;
      *(short8*)(dst + 8) = o1;
    }
  }
  gbar(&bars[0]);

  // ========== P1: t-partials. block = (e, y-tile of 16 tok, z of K=256); ====
  // 4 waves each take K=64 of the z-chunk; in-block LDS reduce -> tpart[z].
  {
    int e = b >> 6, y = (b >> 2) & 15, z = b & 3;
    int end = offs[e + 1];
    int row0 = offs[e] + y * 16;
    if (row0 < end) {
      int k0 = z * 256 + w * 64;
      int pos = row0 + l15;
      int tok = (pos < end) ? perm[pos] : -1;
      const unsigned short* hrow = Hbf + (size_t)(tok < 0 ? 0 : tok) * D + k0;
      const unsigned short* brow = mxT + (size_t)e * 128 * D + k0;
      floatx4 acc[8];
#pragma unroll
      for (int nt = 0; nt < 8; ++nt) acc[nt] = (floatx4){0.f, 0.f, 0.f, 0.f};
#pragma unroll
      for (int ks = 0; ks < 2; ++ks) {
        int kc = ks * 32 + quad * 8;
        short8 a = (short8){0, 0, 0, 0, 0, 0, 0, 0};
        if (tok >= 0) a = *(const short8*)(hrow + kc);
#pragma unroll
        for (int nt = 0; nt < 8; ++nt) {
          short8 bb = *(const short8*)(brow + (size_t)(nt * 16 + l15) * D + kc);
          acc[nt] = __builtin_amdgcn_mfma_f32_16x16x32_bf16(a, bb, acc[nt], 0, 0, 0);
        }
      }
      float* part = (float*)smem;  // [4][16][128] f32 = 32 KB
#pragma unroll
      for (int reg = 0; reg < 4; ++reg)
#pragma unroll
        for (int nt = 0; nt < 8; ++nt)
          part[w * 2048 + (quad * 4 + reg) * 128 + nt * 16 + l15] = acc[nt][reg];
      __syncthreads();
#pragma unroll
      for (int i = 0; i < 8; ++i) {
        int el = t * 8 + i;
        float s = part[el] + part[2048 + el] + part[4096 + el] + part[6144 + el];
        int rr = el >> 7, nn = el & 127;
        int p = row0 + rr;
        if (p < end) tpart[((size_t)z * S + p) * 128 + nn] = s;
      }
    }
  }
  gbar(&bars[1]);

  // ========== P2: tred + inter fused. block = (e, y-tile of 16, pz of 704) ==
  {
    int e = b >> 6, y = (b >> 2) & 15, pz = b & 3;
    int end = offs[e + 1];
    int start = offs[e] + y * 16;
    if (start < end) {
      unsigned short* tb = (unsigned short*)smem;  // [16][128] bf16 = 4 KB
#pragma unroll
      for (int i = 0; i < 8; ++i) {
        int el = t * 8 + i;
        int rr = el >> 7, nn = el & 127;
        int p = start + rr;
        float s = 0.f;
        if (p < end) {
#pragma unroll
          for (int z = 0; z < ZT; ++z) s += tpart[((size_t)z * S + p) * 128 + nn];
        }
        tb[el] = f2bf(s);
      }
      __syncthreads();
      int pbase = pz * 704 + w * 176;
      short8 au[2], ag[2];
#pragma unroll
      for (int ks = 0; ks < 2; ++ks) {
        int kc = ks * 32 + quad * 8;
        au[ks] = *(const short8*)&tb[l15 * 128 + kc];
        ag[ks] = *(const short8*)&tb[l15 * 128 + 64 + kc];
      }
#pragma unroll
      for (int nt = 0; nt < 11; ++nt) {
        floatx4 accu = (floatx4){0.f, 0.f, 0.f, 0.f};
        floatx4 accg = (floatx4){0.f, 0.f, 0.f, 0.f};
        size_t prow = (size_t)e * P + pbase + nt * 16 + l15;
#pragma unroll
        for (int ks = 0; ks < 2; ++ks) {
          int kc = ks * 32 + quad * 8;
          short8 bu = *(const short8*)(Aubf + prow * R + kc);
          short8 bg = *(const short8*)(Agbf + prow * R + kc);
          accu = __builtin_amdgcn_mfma_f32_16x16x32_bf16(au[ks], bu, accu, 0, 0, 0);
          accg = __builtin_amdgcn_mfma_f32_16x16x32_bf16(ag[ks], bg, accg, 0, 0, 0);
        }
#pragma unroll
        for (int reg = 0; reg < 4; ++reg) {
          int pr = start + quad * 4 + reg;
          if (pr < end) {
            float gv = accg[reg], uv = accu[reg];
            float val = uv * (gv / (1.f + __expf(-gv)));
            inter[(size_t)pr * P + pbase + nt * 16 + l15] = f2bf(val);
          }
        }
      }
    }
  }
  gbar(&bars[2]);

  // ========== P3: k_down verbatim (flat LDS). block = (e, kz, dz) ===========
  {
    int e = b >> 6, kz = (b >> 4) & 3, d0 = (b & 15) * 64;
    int start = offs[e];
    int end = offs[e + 1];
    if (start < end) {
      unsigned short* As = (unsigned short*)smem;            // [256][72]
      unsigned short* Bs = (unsigned short*)(smem + 36864);  // [64][72]
      const unsigned short* aptr[8];
      bool aok[8];
#pragma unroll
      for (int j = 0; j < 8; ++j) {
        int arow = (t >> 3) + 32 * j;
        int pos = start + arow;
        aok[j] = (pos < end);
        aptr[j] = inter + (size_t)(aok[j] ? pos : start) * P + kz * KQ + (t & 7) * 8;
      }
      const float* bsrc = Wd + ((size_t)(e * D + d0 + (t >> 2)) * P + kz * KQ + (t & 3) * 16);

      float4 pa[8];
      float4 pb[4];
#pragma unroll
      for (int j = 0; j < 8; ++j)
        pa[j] = aok[j] ? *(const float4*)(aptr[j]) : make_float4(0.f, 0.f, 0.f, 0.f);
#pragma unroll
      for (int q = 0; q < 4; ++q) pb[q] = *(const float4*)(bsrc + q * 4);

      floatx4 acc[4][4];
#pragma unroll
      for (int tt = 0; tt < 4; ++tt)
#pragma unroll
        for (int dt = 0; dt < 4; ++dt) acc[tt][dt] = (floatx4){0.f, 0.f, 0.f, 0.f};

      for (int it = 0; it < NIT; ++it) {
#pragma unroll
        for (int j = 0; j < 8; ++j)
          *(float4*)&As[((t >> 3) + 32 * j) * 72 + (t & 7) * 8] = pa[j];
        *(short8*)&Bs[(t >> 2) * 72 + (t & 3) * 16] = pack8(pb[0], pb[1]);
        *(short8*)&Bs[(t >> 2) * 72 + (t & 3) * 16 + 8] = pack8(pb[2], pb[3]);
        __syncthreads();
        if (it + 1 < NIT) {
          int k0 = (it + 1) * 64;
#pragma unroll
          for (int j = 0; j < 8; ++j)
            pa[j] = aok[j] ? *(const float4*)(aptr[j] + k0) : make_float4(0.f, 0.f, 0.f, 0.f);
#pragma unroll
          for (int q = 0; q < 4; ++q) pb[q] = *(const float4*)(bsrc + k0 + q * 4);
        }
#pragma unroll
        for (int ks = 0; ks < 2; ++ks) {
          int kc = ks * 32 + quad * 8;
          short8 a[4], bb[4];
#pragma unroll
          for (int tt = 0; tt < 4; ++tt)
            a[tt] = *(const short8*)&As[(w * 64 + tt * 16 + l15) * 72 + kc];
#pragma unroll
          for (int dt = 0; dt < 4; ++dt)
            bb[dt] = *(const short8*)&Bs[(dt * 16 + l15) * 72 + kc];
#pragma unroll
          for (int tt = 0; tt < 4; ++tt)
#pragma unroll
            for (int dt = 0; dt < 4; ++dt)
              acc[tt][dt] = __builtin_amdgcn_mfma_f32_16x16x32_bf16(a[tt], bb[dt], acc[tt][dt], 0, 0, 0);
        }
        __syncthreads();
      }
      float* dp = dpart + (size_t)kz * S * D;
#pragma unroll
      for (int tt = 0; tt < 4; ++tt)
#pragma unroll
        for (int reg = 0; reg < 4; ++reg) {
          int pos = start + w * 64 + tt * 16 + quad * 4 + reg;
          if (pos < end) {
#pragma unroll
            for (int dt = 0; dt < 4; ++dt)
              dp[(size_t)pos * D + d0 + dt * 16 + l15] = acc[tt][dt][reg];
          }
        }
    }
  }
  gbar(&bars[3]);

  // ========== P4: reduce K-split partials, apply wt, scatter to out =========
  {
    int row = b * 2 + (t >> 7);
    int l = t & 127;
    int tok = perm[row];
    float wt = wts[tok];
    const float* src = dpart + (size_t)row * D + l * 8;
    float* dst = out + (size_t)tok * D + l * 8;
#pragma unroll
    for (int j = 0; j < 2; ++j) {
      float4 s = *(const float4*)(src + j * 4);
#pragma unroll
      for (int kz = 1; kz < KSPLIT; ++kz) {
        float4 v = *(const float4*)(src + (size_t)kz * S * D + j * 4);
        s.x += v.x; s.y += v.y; s.z += v.z; s.w += v.w;
      }
      s.x *= wt; s.y *= wt; s.z *= wt; s.w *= wt;
      *(float4*)(dst + j * 4) = s;
    }
  }
}

// ---------------------------------------------------------------------------
extern "C" void kernel_launch(void* const* d_in, const int* in_sizes, int n_in,
                              void* d_out, int out_size, void* d_ws, size_t ws_size,
                              hipStream_t stream) {
  const float* H = (const float*)d_in[0];
  const int* idx = (const int*)d_in[1];
  const float* wts = (const float*)d_in[2];
  const float* Aup = (const float*)d_in[3];
  const float* Agate = (const float*)d_in[4];
  const float* upl = (const float*)d_in[5];
  const float* gatel = (const float*)d_in[6];
  const float* Wd = (const float*)d_in[7];
  const float* upb = (const float*)d_in[8];
  const float* gateb = (const float*)d_in[9];
  float* out = (float*)d_out;

  char* ws = (char*)d_ws;
  unsigned short* Hbf = (unsigned short*)ws;                  // S*D bf16 = 2 MB
  unsigned short* mxT = Hbf + (size_t)S * D;                  // E*128*D bf16 = 2 MB
  unsigned short* Aubf = mxT + (size_t)E * 128 * D;           // E*P*R bf16 = 2.9 MB
  unsigned short* Agbf = Aubf + (size_t)E * P * R;            // 2.9 MB
  unsigned short* inter = Agbf + (size_t)E * P * R;           // S*P bf16 = 5.8 MB
  float* tpart = (float*)(inter + (size_t)S * P);             // ZT*S*128 f32 = 2 MB
  float* dpart = tpart + (size_t)ZT * S * 128;                // KSPLIT*S*D f32 = 16 MB
  int* perm = (int*)(dpart + (size_t)KSPLIT * S * D);
  int* offs = perm + S;
  unsigned* bars = (unsigned*)(offs + (E + 1));

  // zero the 4 phase-barrier counters (hipMemsetAsync is graph-capture-legal;
  // the harness itself enqueues hipMemsetAsync)
  hipMemsetAsync(bars, 0, 4 * sizeof(unsigned), stream);
  k_mega<<<NBLK, 256, 0, stream>>>(H, idx, wts, Aup, Agate, upl, gatel, Wd,
                                   upb, gateb, Hbf, mxT, Aubf, Agbf, inter,
                                   tpart, dpart, perm, offs, out, bars);
}

// Round 8
// 392.877 us; speedup vs baseline: 1.6812x; 1.6812x over previous
//
#include <hip/hip_runtime.h>
#include <hip/hip_bf16.h>
#include <math.h>

#define S 1024
#define D 1024
#define P 2816
#define R 64
#define E 8
#define M 16
#define KSPLIT 4
#define KQ (P / KSPLIT)        // 704
#define NIT (KQ / 64)          // 11
#define ZT 4                   // P1 K-split (z) x 4 waves = 16 K-slices of 64
#define ACH ((E * P * R) / 8)  // 180224 adapter short8-chunks
#define NBLK 512

typedef __attribute__((ext_vector_type(8))) short short8;   // 8 bf16 (4 VGPRs)
typedef __attribute__((ext_vector_type(4))) float floatx4;  // MFMA acc

static __device__ inline unsigned short f2bf(float f) {
  __hip_bfloat16 h = __float2bfloat16(f);
  return *reinterpret_cast<unsigned short*>(&h);
}
static __device__ inline short8 pack8(float4 a, float4 b) {
  short8 v;
  v[0] = f2bf(a.x); v[1] = f2bf(a.y); v[2] = f2bf(a.z); v[3] = f2bf(a.w);
  v[4] = f2bf(b.x); v[5] = f2bf(b.y); v[6] = f2bf(b.z); v[7] = f2bf(b.w);
  return v;
}

// Grid barrier, round-8 fix: poll with RELAXED agent-scope load (plain sc1
// load, bypasses the non-coherent XCD L2, NO buffer_inv per poll), then ONE
// ACQUIRE load after exit (single cache-inv per block per barrier). Round-7's
// acquire-in-loop emitted an L1/L2 invalidate EVERY poll iteration; 512
// spinners thrashed the caches of still-working blocks -> 549 us with all
// pipes <1.5% busy. Release ordering lives in the fetch_add(RELEASE).
static __device__ __forceinline__ void gbar(unsigned* ctr) {
  __syncthreads();
  if (threadIdx.x == 0) {
    __hip_atomic_fetch_add(ctr, 1u, __ATOMIC_RELEASE, __HIP_MEMORY_SCOPE_AGENT);
    while (__hip_atomic_load(ctr, __ATOMIC_RELAXED, __HIP_MEMORY_SCOPE_AGENT) < NBLK)
      __builtin_amdgcn_s_sleep(8);
    (void)__hip_atomic_load(ctr, __ATOMIC_ACQUIRE, __HIP_MEMORY_SCOPE_AGENT);
  }
  __syncthreads();
}

// ---------------------------------------------------------------------------
// ONE kernel, 512 blocks x 256 threads, 5 phases split by gbar(). Phase
// bodies identical to round 7 (verified correct). Only gbar changed.
// ---------------------------------------------------------------------------
__global__ __launch_bounds__(256) void k_mega(
    const float* __restrict__ H, const int* __restrict__ idx,
    const float* __restrict__ wts, const float* __restrict__ Aup,
    const float* __restrict__ Agate, const float* __restrict__ upl,
    const float* __restrict__ gatel, const float* __restrict__ Wd,
    const float* __restrict__ upb, const float* __restrict__ gateb,
    unsigned short* __restrict__ Hbf, unsigned short* __restrict__ mxT,
    unsigned short* __restrict__ Aubf, unsigned short* __restrict__ Agbf,
    unsigned short* __restrict__ inter, float* __restrict__ tpart,
    float* __restrict__ dpart, int* __restrict__ perm,
    int* __restrict__ offs, float* __restrict__ out,
    unsigned* __restrict__ bars) {
  __shared__ __align__(16) unsigned char smem[46080];
  int b = blockIdx.x, t = threadIdx.x;
  int lane = t & 63, w = t >> 6, quad = lane >> 4, l15 = lane & 15;

  // ========== P0: sort (b==0) + H/adapter->bf16 (b<256) + mix (256<=b<384) ==
  if (b < 256) {
    int g = b * 256 + t;
    if (b == 0) {  // counting sort, 4 tokens/thread
      int* hist = (int*)smem;
      int* basearr = hist + E;
      if (t < E) hist[t] = 0;
      __syncthreads();
      int e4[4];
#pragma unroll
      for (int j = 0; j < 4; ++j) {
        e4[j] = idx[t + j * 256];
        atomicAdd(&hist[e4[j]], 1);
      }
      __syncthreads();
      if (t == 0) {
        int run = 0;
        for (int i = 0; i < E; ++i) { basearr[i] = run; offs[i] = run; run += hist[i]; }
        offs[E] = S;
      }
      __syncthreads();
#pragma unroll
      for (int j = 0; j < 4; ++j) {
        int pos = atomicAdd(&basearr[e4[j]], 1);
        perm[pos] = t + j * 256;
      }
    }
    // H -> bf16, 16 elems/thread (coalesced)
    {
      const float* hs = H + (size_t)g * 16;
      float4 h0 = *(const float4*)hs, h1 = *(const float4*)(hs + 4);
      float4 h2 = *(const float4*)(hs + 8), h3 = *(const float4*)(hs + 12);
      *(short8*)(Hbf + (size_t)g * 16) = pack8(h0, h1);
      *(short8*)(Hbf + (size_t)g * 16 + 8) = pack8(h2, h3);
    }
    // adapters -> bf16 (strided over short8 chunks)
#pragma unroll
    for (int j = 0; j < 3; ++j) {
      int c = g + j * 65536;
      if (c < ACH) {
        const float* su = Aup + (size_t)c * 8;
        const float* sg = Agate + (size_t)c * 8;
        float4 u0 = *(const float4*)su, u1 = *(const float4*)(su + 4);
        float4 g0 = *(const float4*)sg, g1 = *(const float4*)(sg + 4);
        *(short8*)(Aubf + (size_t)c * 8) = pack8(u0, u1);
        *(short8*)(Agbf + (size_t)c * 8) = pack8(g0, g1);
      }
    }
  } else if (b < 384) {
    // mix: block = (mat, d0 of 16). Bank read once, coalesced over r;
    // LDS-transposed; mxT written in contiguous 32B row-chunks.
    int mb = b - 256;
    int mat = mb >> 6, d0 = (mb & 63) * 16;
    const float* bank = mat ? gateb : upb;
    float* tile = (float*)smem;              // [E][64][17] f32 = 34816 B
    float* alpha = (float*)(smem + 34816);   // [E][M] = 512 B
    if (t < E) {
      const float* lg = (mat ? gatel : upl) + t * M;
      float v[M], mx = -1e30f, s = 0.f;
#pragma unroll
      for (int m = 0; m < M; ++m) { v[m] = lg[m]; mx = fmaxf(mx, v[m]); }
#pragma unroll
      for (int m = 0; m < M; ++m) { v[m] = expf(v[m] - mx); s += v[m]; }
#pragma unroll
      for (int m = 0; m < M; ++m) alpha[t * M + m] = v[m] / s;
    }
    __syncthreads();
    int r4 = (t & 15) * 4;  // r base: thread covers r4..r4+3
    int dg = t >> 4;        // d-local 0..15
    float val[E][4];
#pragma unroll
    for (int e = 0; e < E; ++e)
#pragma unroll
      for (int i = 0; i < 4; ++i) val[e][i] = 0.f;
    for (int m = 0; m < M; ++m) {
      float4 bv = *(const float4*)(bank + ((size_t)m * D + d0 + dg) * R + r4);
#pragma unroll
      for (int e = 0; e < E; ++e) {
        float a = alpha[e * M + m];
        val[e][0] += a * bv.x; val[e][1] += a * bv.y;
        val[e][2] += a * bv.z; val[e][3] += a * bv.w;
      }
    }
#pragma unroll
    for (int e = 0; e < E; ++e)
#pragma unroll
      for (int i = 0; i < 4; ++i) tile[((size_t)e * 64 + r4 + i) * 17 + dg] = val[e][i];
    __syncthreads();
    int e = t >> 5;
#pragma unroll
    for (int half = 0; half < 2; ++half) {
      int rr = (t & 31) + half * 32;
      short8 o0, o1;
#pragma unroll
      for (int j = 0; j < 8; ++j) {
        o0[j] = (short)f2bf(tile[((size_t)e * 64 + rr) * 17 + j]);
        o1[j] = (short)f2bf(tile[((size_t)e * 64 + rr) * 17 + 8 + j]);
      }
      unsigned short* dst = mxT + ((size_t)(e * 128 + mat * 64 + rr)) * D + d0;
      *(short8*)dst = o0;
      *(short8*)(dst + 8) = o1;
    }
  }
  gbar(&bars[0]);

  // ========== P1: t-partials. block = (e, y-tile of 16 tok, z of K=256); ====
  // 4 waves each take K=64 of the z-chunk; in-block LDS reduce -> tpart[z].
  {
    int e = b >> 6, y = (b >> 2) & 15, z = b & 3;
    int end = offs[e + 1];
    int row0 = offs[e] + y * 16;
    if (row0 < end) {
      int k0 = z * 256 + w * 64;
      int pos = row0 + l15;
      int tok = (pos < end) ? perm[pos] : -1;
      const unsigned short* hrow = Hbf + (size_t)(tok < 0 ? 0 : tok) * D + k0;
      const unsigned short* brow = mxT + (size_t)e * 128 * D + k0;
      floatx4 acc[8];
#pragma unroll
      for (int nt = 0; nt < 8; ++nt) acc[nt] = (floatx4){0.f, 0.f, 0.f, 0.f};
#pragma unroll
      for (int ks = 0; ks < 2; ++ks) {
        int kc = ks * 32 + quad * 8;
        short8 a = (short8){0, 0, 0, 0, 0, 0, 0, 0};
        if (tok >= 0) a = *(const short8*)(hrow + kc);
#pragma unroll
        for (int nt = 0; nt < 8; ++nt) {
          short8 bb = *(const short8*)(brow + (size_t)(nt * 16 + l15) * D + kc);
          acc[nt] = __builtin_amdgcn_mfma_f32_16x16x32_bf16(a, bb, acc[nt], 0, 0, 0);
        }
      }
      float* part = (float*)smem;  // [4][16][128] f32 = 32 KB
#pragma unroll
      for (int reg = 0; reg < 4; ++reg)
#pragma unroll
        for (int nt = 0; nt < 8; ++nt)
          part[w * 2048 + (quad * 4 + reg) * 128 + nt * 16 + l15] = acc[nt][reg];
      __syncthreads();
#pragma unroll
      for (int i = 0; i < 8; ++i) {
        int el = t * 8 + i;
        float s = part[el] + part[2048 + el] + part[4096 + el] + part[6144 + el];
        int rr = el >> 7, nn = el & 127;
        int p = row0 + rr;
        if (p < end) tpart[((size_t)z * S + p) * 128 + nn] = s;
      }
    }
  }
  gbar(&bars[1]);

  // ========== P2: tred + inter fused. block = (e, y-tile of 16, pz of 704) ==
  {
    int e = b >> 6, y = (b >> 2) & 15, pz = b & 3;
    int end = offs[e + 1];
    int start = offs[e] + y * 16;
    if (start < end) {
      unsigned short* tb = (unsigned short*)smem;  // [16][128] bf16 = 4 KB
#pragma unroll
      for (int i = 0; i < 8; ++i) {
        int el = t * 8 + i;
        int rr = el >> 7, nn = el & 127;
        int p = start + rr;
        float s = 0.f;
        if (p < end) {
#pragma unroll
          for (int z = 0; z < ZT; ++z) s += tpart[((size_t)z * S + p) * 128 + nn];
        }
        tb[el] = f2bf(s);
      }
      __syncthreads();
      int pbase = pz * 704 + w * 176;
      short8 au[2], ag[2];
#pragma unroll
      for (int ks = 0; ks < 2; ++ks) {
        int kc = ks * 32 + quad * 8;
        au[ks] = *(const short8*)&tb[l15 * 128 + kc];
        ag[ks] = *(const short8*)&tb[l15 * 128 + 64 + kc];
      }
#pragma unroll
      for (int nt = 0; nt < 11; ++nt) {
        floatx4 accu = (floatx4){0.f, 0.f, 0.f, 0.f};
        floatx4 accg = (floatx4){0.f, 0.f, 0.f, 0.f};
        size_t prow = (size_t)e * P + pbase + nt * 16 + l15;
#pragma unroll
        for (int ks = 0; ks < 2; ++ks) {
          int kc = ks * 32 + quad * 8;
          short8 bu = *(const short8*)(Aubf + prow * R + kc);
          short8 bg = *(const short8*)(Agbf + prow * R + kc);
          accu = __builtin_amdgcn_mfma_f32_16x16x32_bf16(au[ks], bu, accu, 0, 0, 0);
          accg = __builtin_amdgcn_mfma_f32_16x16x32_bf16(ag[ks], bg, accg, 0, 0, 0);
        }
#pragma unroll
        for (int reg = 0; reg < 4; ++reg) {
          int pr = start + quad * 4 + reg;
          if (pr < end) {
            float gv = accg[reg], uv = accu[reg];
            float val = uv * (gv / (1.f + __expf(-gv)));
            inter[(size_t)pr * P + pbase + nt * 16 + l15] = f2bf(val);
          }
        }
      }
    }
  }
  gbar(&bars[2]);

  // ========== P3: k_down verbatim (flat LDS). block = (e, kz, dz) ===========
  {
    int e = b >> 6, kz = (b >> 4) & 3, d0 = (b & 15) * 64;
    int start = offs[e];
    int end = offs[e + 1];
    if (start < end) {
      unsigned short* As = (unsigned short*)smem;            // [256][72]
      unsigned short* Bs = (unsigned short*)(smem + 36864);  // [64][72]
      const unsigned short* aptr[8];
      bool aok[8];
#pragma unroll
      for (int j = 0; j < 8; ++j) {
        int arow = (t >> 3) + 32 * j;
        int pos = start + arow;
        aok[j] = (pos < end);
        aptr[j] = inter + (size_t)(aok[j] ? pos : start) * P + kz * KQ + (t & 7) * 8;
      }
      const float* bsrc = Wd + ((size_t)(e * D + d0 + (t >> 2)) * P + kz * KQ + (t & 3) * 16);

      float4 pa[8];
      float4 pb[4];
#pragma unroll
      for (int j = 0; j < 8; ++j)
        pa[j] = aok[j] ? *(const float4*)(aptr[j]) : make_float4(0.f, 0.f, 0.f, 0.f);
#pragma unroll
      for (int q = 0; q < 4; ++q) pb[q] = *(const float4*)(bsrc + q * 4);

      floatx4 acc[4][4];
#pragma unroll
      for (int tt = 0; tt < 4; ++tt)
#pragma unroll
        for (int dt = 0; dt < 4; ++dt) acc[tt][dt] = (floatx4){0.f, 0.f, 0.f, 0.f};

      for (int it = 0; it < NIT; ++it) {
#pragma unroll
        for (int j = 0; j < 8; ++j)
          *(float4*)&As[((t >> 3) + 32 * j) * 72 + (t & 7) * 8] = pa[j];
        *(short8*)&Bs[(t >> 2) * 72 + (t & 3) * 16] = pack8(pb[0], pb[1]);
        *(short8*)&Bs[(t >> 2) * 72 + (t & 3) * 16 + 8] = pack8(pb[2], pb[3]);
        __syncthreads();
        if (it + 1 < NIT) {
          int k0 = (it + 1) * 64;
#pragma unroll
          for (int j = 0; j < 8; ++j)
            pa[j] = aok[j] ? *(const float4*)(aptr[j] + k0) : make_float4(0.f, 0.f, 0.f, 0.f);
#pragma unroll
          for (int q = 0; q < 4; ++q) pb[q] = *(const float4*)(bsrc + k0 + q * 4);
        }
#pragma unroll
        for (int ks = 0; ks < 2; ++ks) {
          int kc = ks * 32 + quad * 8;
          short8 a[4], bb[4];
#pragma unroll
          for (int tt = 0; tt < 4; ++tt)
            a[tt] = *(const short8*)&As[(w * 64 + tt * 16 + l15) * 72 + kc];
#pragma unroll
          for (int dt = 0; dt < 4; ++dt)
            bb[dt] = *(const short8*)&Bs[(dt * 16 + l15) * 72 + kc];
#pragma unroll
          for (int tt = 0; tt < 4; ++tt)
#pragma unroll
            for (int dt = 0; dt < 4; ++dt)
              acc[tt][dt] = __builtin_amdgcn_mfma_f32_16x16x32_bf16(a[tt], bb[dt], acc[tt][dt], 0, 0, 0);
        }
        __syncthreads();
      }
      float* dp = dpart + (size_t)kz * S * D;
#pragma unroll
      for (int tt = 0; tt < 4; ++tt)
#pragma unroll
        for (int reg = 0; reg < 4; ++reg) {
          int pos = start + w * 64 + tt * 16 + quad * 4 + reg;
          if (pos < end) {
#pragma unroll
            for (int dt = 0; dt < 4; ++dt)
              dp[(size_t)pos * D + d0 + dt * 16 + l15] = acc[tt][dt][reg];
          }
        }
    }
  }
  gbar(&bars[3]);

  // ========== P4: reduce K-split partials, apply wt, scatter to out =========
  {
    int row = b * 2 + (t >> 7);
    int l = t & 127;
    int tok = perm[row];
    float wt = wts[tok];
    const float* src = dpart + (size_t)row * D + l * 8;
    float* dst = out + (size_t)tok * D + l * 8;
#pragma unroll
    for (int j = 0; j < 2; ++j) {
      float4 s = *(const float4*)(src + j * 4);
#pragma unroll
      for (int kz = 1; kz < KSPLIT; ++kz) {
        float4 v = *(const float4*)(src + (size_t)kz * S * D + j * 4);
        s.x += v.x; s.y += v.y; s.z += v.z; s.w += v.w;
      }
      s.x *= wt; s.y *= wt; s.z *= wt; s.w *= wt;
      *(float4*)(dst + j * 4) = s;
    }
  }
}

// ---------------------------------------------------------------------------
extern "C" void kernel_launch(void* const* d_in, const int* in_sizes, int n_in,
                              void* d_out, int out_size, void* d_ws, size_t ws_size,
                              hipStream_t stream) {
  const float* H = (const float*)d_in[0];
  const int* idx = (const int*)d_in[1];
  const float* wts = (const float*)d_in[2];
  const float* Aup = (const float*)d_in[3];
  const float* Agate = (const float*)d_in[4];
  const float* upl = (const float*)d_in[5];
  const float* gatel = (const float*)d_in[6];
  const float* Wd = (const float*)d_in[7];
  const float* upb = (const float*)d_in[8];
  const float* gateb = (const float*)d_in[9];
  float* out = (float*)d_out;

  char* ws = (char*)d_ws;
  unsigned short* Hbf = (unsigned short*)ws;                  // S*D bf16 = 2 MB
  unsigned short* mxT = Hbf + (size_t)S * D;                  // E*128*D bf16 = 2 MB
  unsigned short* Aubf = mxT + (size_t)E * 128 * D;           // E*P*R bf16 = 2.9 MB
  unsigned short* Agbf = Aubf + (size_t)E * P * R;            // 2.9 MB
  unsigned short* inter = Agbf + (size_t)E * P * R;           // S*P bf16 = 5.8 MB
  float* tpart = (float*)(inter + (size_t)S * P);             // ZT*S*128 f32 = 2 MB
  float* dpart = tpart + (size_t)ZT * S * 128;                // KSPLIT*S*D f32 = 16 MB
  int* perm = (int*)(dpart + (size_t)KSPLIT * S * D);
  int* offs = perm + S;
  unsigned* bars = (unsigned*)(offs + (E + 1));

  // zero the 4 phase-barrier counters (hipMemsetAsync is graph-capture-legal)
  hipMemsetAsync(bars, 0, 4 * sizeof(unsigned), stream);
  k_mega<<<NBLK, 256, 0, stream>>>(H, idx, wts, Aup, Agate, upl, gatel, Wd,
                                   upb, gateb, Hbf, mxT, Aubf, Agbf, inter,
                                   tpart, dpart, perm, offs, out, bars);
}